// Round 1
// baseline (107.329 us; speedup 1.0000x reference)
//
#include <hip/hip_runtime.h>

#define MAXL 33
#define SIGMA_DIS 3.0f

// ---------------------------------------------------------------------------
// Kernel 1: per-(batch,label) segmented sum of sq = sum_c pred^2 and counts.
// Layout: pred [B, C=4, N] f32, labels [B, N] i32. Each thread handles 4
// consecutive pixels per iteration (float4 per channel + int4 labels).
// Accumulate into per-block LDS histograms, flush with global float atomics.
// ---------------------------------------------------------------------------
__global__ __launch_bounds__(256) void seg_hist_kernel(
    const float* __restrict__ pred, const int* __restrict__ labels,
    float* __restrict__ acc_ssq, float* __restrict__ acc_cnt, int N) {
  const int b = blockIdx.y;
  const int ng = N >> 2;  // float4 groups per image
  __shared__ float h_ssq[MAXL];
  __shared__ float h_cnt[MAXL];
  const int tid = threadIdx.x;
  if (tid < MAXL) {
    h_ssq[tid] = 0.f;
    h_cnt[tid] = 0.f;
  }
  __syncthreads();

  const float4* p = reinterpret_cast<const float4*>(pred) + (size_t)b * 4 * ng;
  const int4* lb = reinterpret_cast<const int4*>(labels) + (size_t)b * ng;

  for (int g = blockIdx.x * blockDim.x + tid; g < ng;
       g += gridDim.x * blockDim.x) {
    float4 c0 = p[g];
    float4 c1 = p[g + ng];
    float4 c2 = p[g + 2 * ng];
    float4 c3 = p[g + 3 * ng];
    int4 l = lb[g];
    float s0 = c0.x * c0.x + c1.x * c1.x + c2.x * c2.x + c3.x * c3.x;
    float s1 = c0.y * c0.y + c1.y * c1.y + c2.y * c2.y + c3.y * c3.y;
    float s2 = c0.z * c0.z + c1.z * c1.z + c2.z * c2.z + c3.z * c3.z;
    float s3 = c0.w * c0.w + c1.w * c1.w + c2.w * c2.w + c3.w * c3.w;
    atomicAdd(&h_ssq[l.x], s0);
    atomicAdd(&h_cnt[l.x], 1.f);
    atomicAdd(&h_ssq[l.y], s1);
    atomicAdd(&h_cnt[l.y], 1.f);
    atomicAdd(&h_ssq[l.z], s2);
    atomicAdd(&h_cnt[l.z], 1.f);
    atomicAdd(&h_ssq[l.w], s3);
    atomicAdd(&h_cnt[l.w], 1.f);
  }
  __syncthreads();
  if (tid < MAXL) {
    atomicAdd(&acc_ssq[b * MAXL + tid], h_ssq[tid]);
    atomicAdd(&acc_cnt[b * MAXL + tid], h_cnt[tid]);
  }
}

// ---------------------------------------------------------------------------
// Kernel 2 (single block): s = ssq/card^2, nk = max present label, sum over
// valid unordered pairs of log((sigma - sqrt(s_i+s_j))^2 + 1) / (nk*(nk-1)).
// ---------------------------------------------------------------------------
__global__ __launch_bounds__(256) void finalize_kernel(
    const float* __restrict__ acc_ssq, const float* __restrict__ acc_cnt,
    float* __restrict__ out, int B) {
  __shared__ float s_val[8 * MAXL];
  __shared__ float s_flag[8 * MAXL];  // valid: l>=1 && card>0
  __shared__ float s_invden[8];
  __shared__ float s_part[4];
  const int tid = threadIdx.x;

  for (int i = tid; i < B * MAXL; i += blockDim.x) {
    float cnt = acc_cnt[i];
    float ssq = acc_ssq[i];
    float safe = cnt > 0.f ? cnt : 1.f;
    s_val[i] = ssq / (safe * safe);
    int l = i % MAXL;
    s_flag[i] = (l >= 1 && cnt > 0.f) ? 1.f : 0.f;
  }
  __syncthreads();
  if (tid < B) {
    // nk = max label present (counts > 0); labels with cnt>0 are <= nk by def.
    int nk = 0;
    for (int l = MAXL - 1; l >= 0; --l) {
      if (acc_cnt[tid * MAXL + l] > 0.f) {
        nk = l;
        break;
      }
    }
    s_invden[tid] = (nk > 1) ? 1.0f / ((float)nk * (float)(nk - 1)) : 0.f;
  }
  __syncthreads();

  float local = 0.f;
  const int total = B * MAXL * MAXL;
  for (int idx = tid; idx < total; idx += blockDim.x) {
    int b = idx / (MAXL * MAXL);
    int r = idx - b * MAXL * MAXL;
    int i = r / MAXL;
    int j = r - i * MAXL;
    if (i < j) {
      float m = s_flag[b * MAXL + i] * s_flag[b * MAXL + j];
      if (m != 0.f) {
        float S = s_val[b * MAXL + i] + s_val[b * MAXL + j];
        float d = SIGMA_DIS - sqrtf(S);
        local += logf(d * d + 1.f) * s_invden[b];
      }
    }
  }
  // wave64 shuffle reduce, then cross-wave via LDS
  for (int off = 32; off > 0; off >>= 1) local += __shfl_down(local, off, 64);
  const int wave = tid >> 6;
  if ((tid & 63) == 0) s_part[wave] = local;
  __syncthreads();
  if (tid == 0) {
    float tot = 0.f;
    for (int w = 0; w < 4; ++w) tot += s_part[w];
    out[0] = tot;
  }
}

extern "C" void kernel_launch(void* const* d_in, const int* in_sizes, int n_in,
                              void* d_out, int out_size, void* d_ws,
                              size_t ws_size, hipStream_t stream) {
  const float* pred = (const float*)d_in[0];
  // d_in[1] = kernels_mask: unused by the reference math -> never read.
  const int* labels = (const int*)d_in[2];
  float* out = (float*)d_out;

  const int B = 8;
  const int N = in_sizes[2] / B;  // 896*896 = 802816, divisible by 4

  float* acc_ssq = (float*)d_ws;
  float* acc_cnt = acc_ssq + B * MAXL;
  // d_ws is poisoned (0xAA) before timing and never re-zeroed: clear it here.
  hipMemsetAsync(d_ws, 0, 2 * B * MAXL * sizeof(float), stream);

  dim3 grid(256, B);  // 2048 blocks total, grid-stride over N/4 groups
  seg_hist_kernel<<<grid, dim3(256), 0, stream>>>(pred, labels, acc_ssq,
                                                  acc_cnt, N);
  finalize_kernel<<<dim3(1), dim3(256), 0, stream>>>(acc_ssq, acc_cnt, out, B);
}